// Round 1
// baseline (917.064 us; speedup 1.0000x reference)
//
#include <hip/hip_runtime.h>
#include <math.h>

#define NB 16    // batch
#define SS 256   // spatial size (H = W = 256)
#define DV 32    // channels
#define MM 12    // w-dim (j) modes kept
#define MK 24    // h-dim (iy) modes kept (0..11 and 244..255)
#define LL 4     // layers
#define TWO_PI_N 0.024543692606170259679f   // 2*pi/256
#define HSTR 257 // fused-kernel LDS row stride (floats): 257 % 32 = 1 -> 2-way max (free)

typedef float v2f __attribute__((ext_vector_type(2)));   // -> v_pk_fma_f32

// Workspace (floats):
//   h   : [NB][DV][SS][SS]            134 MB, in-place per layer
//   A   : [NB][MM][DV][SS(iy)][2]     12.6 MB  (row-DFT of h)
//   F   : [NB][ky:MM][m:MK][co:DV][2]  1.2 MB  (mixed spectral coeffs, pre-scaled)
//   g   : [NB][SS(iy)][MM][DV][2]     12.6 MB  (per-row spectral coeffs)
//   twT : [SS][MM][2]                  24 KB   (cos, -sin) of 2*pi*ky*j/256  (fwd DFT)
//   wT  : [LL][ci][co]                 16 KB   (transposed conv weights)
//   tw2 : [MM][SS][2]                  24 KB   (cos, +sin)  (inverse j-DFT, coalesced)

// --------------------------------------------- setup: tables + weight^T
__global__ __launch_bounds__(256) void k_prep(const float* __restrict__ ws_w,
        float* __restrict__ twT, float* __restrict__ wT, float* __restrict__ tw2)
{
    int j = threadIdx.x;
    #pragma unroll
    for (int k = 0; k < MM; ++k) {
        float ang = TWO_PI_N * (float)((k * j) & 255);
        float s, c; sincosf(ang, &s, &c);
        twT[j * (MM * 2) + 2 * k]     = c;
        twT[j * (MM * 2) + 2 * k + 1] = -s;
        tw2[(k * SS + j) * 2]     = c;
        tw2[(k * SS + j) * 2 + 1] = s;
    }
    for (int idx = threadIdx.x; idx < LL * DV * DV; idx += 256) {
        int l = idx >> 10, rem = idx & 1023, co = rem >> 5, ci = rem & 31;
        wT[(l * DV + ci) * DV + co] = ws_w[(l * DV + co) * DV + ci];
    }
}

// ---------------------------------------------------------------------------
// Fused row-DFT epilogue (replaces the standalone k_rowdft global pass).
// Precondition: smem[c*HSTR + j] holds this (b,iy) row for all 32 channels,
// block = 256 threads, __syncthreads() already issued after the stores.
// Thread (c = tid&31, seg = tid>>5) accumulates 32 j's for one channel,
// 12 packed (cos,-sin) FMAs per j (same math as the proven k_rowdft core).
// LDS reads: addr = c*257 + seg*32 + i -> bank (c+i)%32, 2 lanes/bank = free.
// Reduction: 8 seg-partials per (c,k) via LDS (red aliases the hs region).
// ---------------------------------------------------------------------------
__device__ __forceinline__ void row_dft_from_lds(float* smem,
        const float* __restrict__ twT, float* __restrict__ A,
        int b, int iy, int tid)
{
    int c   = tid & 31;
    int seg = tid >> 5;          // 0..7, wave = {2 segs} x {32 c}
    int j0  = seg << 5;

    v2f arai[MM];
    #pragma unroll
    for (int k = 0; k < MM; ++k) arai[k] = (v2f)(0.f);

    const float* hp = smem + c * HSTR + j0;
    #pragma unroll 2
    for (int i = 0; i < 32; ++i) {
        float v = hp[i];
        const float4* twj = (const float4*)(twT + (size_t)(j0 + i) * (MM * 2));
        #pragma unroll
        for (int kk = 0; kk < 6; ++kk) {   // dwordx4 twiddle loads: 2 modes each
            float4 t = twj[kk];
            v2f t0; t0.x = t.x; t0.y = t.y;
            v2f t1; t1.x = t.z; t1.y = t.w;
            arai[2 * kk]     += t0 * v;    // packed (cos,-sin) fma
            arai[2 * kk + 1] += t1 * v;
        }
    }

    __syncthreads();                       // hs reads done; reuse region as red
    v2f* red = (v2f*)smem;                 // [tid][13] v2f (pad 13: no conflicts)
    #pragma unroll
    for (int k = 0; k < MM; ++k) red[tid * 13 + k] = arai[k];
    __syncthreads();

    // 384 outputs (k,c): o = k*32 + c. Threads 0..255 take o, 0..127 also o+256.
    #pragma unroll
    for (int rep = 0; rep < 2; ++rep) {
        int o = tid + rep * 256;
        if (o < 384) {
            int k = o >> 5, cc = o & 31;
            v2f s = (v2f)(0.f);
            #pragma unroll
            for (int sg = 0; sg < 8; ++sg)
                s += red[(sg * 32 + cc) * 13 + k];
            size_t off = ((((size_t)b * MM + k) * DV + cc) * SS + iy) * 2;
            A[off]     = s.x;
            A[off + 1] = s.y;
        }
    }
}

// ------------------------------------------- lifting fused with row-DFT(l=0)
// grid = NB*SS (one row per block); 256 threads, 1 px/thread.
__global__ __launch_bounds__(256, 4) void k_liftdft(const float* __restrict__ x,
        const float* __restrict__ p_w, const float* __restrict__ p_b,
        float* __restrict__ h, const float* __restrict__ twT, float* __restrict__ A)
{
    __shared__ float smem[DV * HSTR];      // 32.9 KB -> 4 blocks/CU
    int tid = threadIdx.x;
    int b  = blockIdx.x >> 8;
    int iy = blockIdx.x & 255;
    int j  = tid;

    float xv = x[((size_t)(b * SS + iy)) * SS + j];
    float gy = -1.f + 2.f * (float)iy * (1.f / 255.f);
    float gx = -1.f + 2.f * (float)j  * (1.f / 255.f);

    float* hb = h + ((size_t)b * DV * SS + iy) * SS + j;
    #pragma unroll
    for (int c = 0; c < DV; ++c) {
        float v = p_w[3*c] * xv + p_w[3*c+1] * gy + p_w[3*c+2] * gx + p_b[c];
        *(hb + (size_t)c * SS * SS) = v;
        smem[c * HSTR + j] = v;            // bank (c+j)%32: conflict-free
    }
    __syncthreads();
    row_dft_from_lds(smem, twT, A, b, iy, tid);
}

// ----------------- pointwise fused with row-DFT for the NEXT layer.
// h = relu(conv1x1(h) + invDFT(g)) in place, then A = rowDFT(h) from LDS.
// grid = NB*SS (one row per block); 256 threads, 1 px/thread.
// Phase A math identical to the R14-proven k_pt (scalar float, s_load g/w).
__global__ __launch_bounds__(256, 4) void k_ptdft(float* __restrict__ h,
        const float* __restrict__ g, const float* __restrict__ wT,
        const float* __restrict__ ws_b, const float* __restrict__ tw2,
        const float* __restrict__ twT, float* __restrict__ A, int l)
{
    __shared__ float smem[DV * HSTR];      // 32.9 KB -> 4 blocks/CU (16 waves)
    int tid = threadIdx.x;
    int b  = blockIdx.x >> 8;
    int iy = blockIdx.x & 255;
    int j  = tid;

    float* hb = h + ((size_t)b * DV * SS + iy) * SS + j;
    const float* wt  = wT + (size_t)l * DV * DV;     // [ci][co], uniform
    const float* wsb = ws_b + (size_t)l * DV;

    float acc[DV];
    #pragma unroll
    for (int co = 0; co < DV; ++co) acc[co] = wsb[co];

    #pragma unroll 4
    for (int ci = 0; ci < DV; ++ci) {
        float hv = *(hb + (size_t)ci * SS * SS);
        const float* wc = wt + ci * DV;              // 32 contiguous s_loads
        #pragma unroll
        for (int co = 0; co < DV; ++co) acc[co] += wc[co] * hv;
    }

    const float* gp = g + ((size_t)(b * SS + iy)) * (MM * DV * 2);  // uniform
    #pragma unroll 2
    for (int ky = 0; ky < MM; ++ky) {
        float2 t2 = *(const float2*)(tw2 + ((size_t)ky * SS + j) * 2);
        const float* Gk = gp + ky * (DV * 2);        // 64 contiguous s_loads
        #pragma unroll
        for (int co = 0; co < DV; ++co) {
            float gr = Gk[2 * co], gi = Gk[2 * co + 1];
            acc[co] += gr * t2.x - gi * t2.y;
        }
    }

    #pragma unroll
    for (int co = 0; co < DV; ++co) {
        float v = fmaxf(acc[co], 0.f);               // all fused layers relu
        *(hb + (size_t)co * SS * SS) = v;
        smem[co * HSTR + j] = v;                     // conflict-free
    }
    __syncthreads();
    row_dft_from_lds(smem, twT, A, b, iy, tid);
}

// ---------- iy-DFT of A + channel mix -> F (pre-scaled)  (unchanged, proven)
__global__ __launch_bounds__(256, 4) void k_cm(const float* __restrict__ A,
        const float* __restrict__ w1r, const float* __restrict__ w1i,
        const float* __restrict__ w2r, const float* __restrict__ w2i,
        float* __restrict__ F, int l)
{
    __shared__ float FinS[DV][6][2];
    int blk = blockIdx.x;
    int mg = blk & 3;
    int bk = blk >> 2;                       // b*MM + ky
    int ky = bk % MM;
    int tid = threadIdx.x;
    int c = tid >> 3, ch = tid & 7;
    int iy0 = ch * 32;

    const float2* Ap = (const float2*)(A + ((size_t)bk * DV + c) * SS * 2);

    float fr[6], fi[6], pc[6], ps[6], sc[6], ssn[6];
    #pragma unroll
    for (int k = 0; k < 6; ++k) {
        int m = mg * 6 + k;
        int f = (m < MM) ? m : (232 + m);    // 244..255 for m >= 12
        float s, cc;
        sincosf(TWO_PI_N * (float)f, &s, &cc);
        sc[k] = cc; ssn[k] = s;
        sincosf(TWO_PI_N * (float)((f * iy0) & 255), &s, &cc);
        pc[k] = cc; ps[k] = s;
        fr[k] = fi[k] = 0.f;
    }
    #pragma unroll 4
    for (int i = 0; i < 32; ++i) {
        float2 a = Ap[iy0 + i];
        #pragma unroll
        for (int k = 0; k < 6; ++k) {
            fr[k] += a.x * pc[k] + a.y * ps[k];   // A * e^{-i th}
            fi[k] += a.y * pc[k] - a.x * ps[k];
            float np = pc[k] * sc[k] - ps[k] * ssn[k];
            float nq = pc[k] * ssn[k] + ps[k] * sc[k];
            pc[k] = np; ps[k] = nq;
        }
    }
    #pragma unroll
    for (int m = 1; m < 8; m <<= 1) {
        #pragma unroll
        for (int k = 0; k < 6; ++k) {
            fr[k] += __shfl_xor(fr[k], m, 64);
            fi[k] += __shfl_xor(fi[k], m, 64);
        }
    }
    #pragma unroll
    for (int k = 0; k < 6; ++k) {
        if (ch == k) { FinS[c][k][0] = fr[k]; FinS[c][k][1] = fi[k]; }
    }
    __syncthreads();

    if (ch < 6) {
        int o = c;
        int m = mg * 6 + ch;
        const float* Wr; const float* Wi; int xm;
        if (m < MM) { Wr = w1r; Wi = w1i; xm = m; }
        else        { Wr = w2r; Wi = w2i; xm = m - MM; }
        float scale = ((ky == 0) ? 1.0f : 2.0f) * (1.0f / 65536.0f);
        float orr = 0.f, oii = 0.f;
        #pragma unroll 4
        for (int i = 0; i < DV; ++i) {
            float gr = FinS[i][ch][0], gi = FinS[i][ch][1];
            size_t wi = ((size_t)(l * DV + i) * DV + o) * (MM * MM) + xm * MM + ky;
            float wr = Wr[wi], wim = Wi[wi];
            orr += gr * wr - gi * wim;
            oii += gr * wim + gi * wr;
        }
        size_t off = (((size_t)bk * MK + m) * DV + o) * 2;   // [ky][m][co]
        F[off] = orr * scale; F[off + 1] = oii * scale;
    }
}

// -------------------- inverse iy-DFT: F -> g[b][iy][ky][co][2]  (unchanged)
__global__ __launch_bounds__(384) void k_inv1(const float* __restrict__ F,
        float* __restrict__ g)
{
    __shared__ float itw[MK * 2];
    int tid = threadIdx.x;
    int b = blockIdx.x >> 8, iy = blockIdx.x & 255;
    if (tid < MK) {
        int f = (tid < MM) ? tid : (232 + tid);
        float ang = TWO_PI_N * (float)((f * iy) & 255);
        float s, c; sincosf(ang, &s, &c);
        itw[2 * tid] = c; itw[2 * tid + 1] = s;
    }
    __syncthreads();

    int ky = tid >> 5, co = tid & 31;
    const float* Fp = F + ((size_t)(b * MM + ky) * MK) * (DV * 2) + 2 * co;
    float gr = 0.f, gi = 0.f;
    #pragma unroll
    for (int m = 0; m < MK; ++m) {
        float2 fv = *(const float2*)(Fp + (size_t)m * (DV * 2));  // coalesced
        float ic = itw[2 * m], is = itw[2 * m + 1];
        gr += fv.x * ic - fv.y * is;
        gi += fv.x * is + fv.y * ic;
    }
    size_t o = (((size_t)(b * SS + iy)) * MM + ky) * (DV * 2) + 2 * co;
    g[o] = gr; g[o + 1] = gi;
}

// ----------------- FINAL-layer pointwise (projection to out); no DFT needed.
// grid = NB*128; block = 2 rows x 2 j-halves, 2 px/thread. R14-proven form.
template<int FINAL>
__global__ __launch_bounds__(256, 4) void k_pt(float* __restrict__ h,
        const float* __restrict__ g, const float* __restrict__ wT,
        const float* __restrict__ ws_b, const float* __restrict__ tw2,
        const float* __restrict__ q_w, const float* __restrict__ q_b,
        float* __restrict__ out, int l)
{
    int tid = threadIdx.x;
    int lane = tid & 63;
    int w = __builtin_amdgcn_readfirstlane(tid >> 6);
    int b  = blockIdx.x >> 7;
    int iy = ((blockIdx.x & 127) << 1) + (w >> 1);
    int j0 = ((w & 1) << 7) + (lane << 1);

    float* hb = h + ((size_t)b * DV * SS + iy) * SS + j0;
    const float* wt  = wT + (size_t)l * DV * DV;     // [ci][co], uniform
    const float* wsb = ws_b + (size_t)l * DV;

    float2 acc[DV];
    #pragma unroll
    for (int co = 0; co < DV; ++co) {
        float bv = wsb[co];
        acc[co].x = bv; acc[co].y = bv;
    }

    #pragma unroll 4
    for (int ci = 0; ci < DV; ++ci) {
        float2 hv = *(const float2*)(hb + (size_t)ci * SS * SS);
        const float* wc = wt + ci * DV;              // 32 contiguous s_loads
        #pragma unroll
        for (int co = 0; co < DV; ++co) {
            float wv = wc[co];
            acc[co].x += wv * hv.x; acc[co].y += wv * hv.y;
        }
    }

    const float* gp = g + ((size_t)(b * SS + iy)) * (MM * DV * 2);  // uniform
    #pragma unroll 2
    for (int ky = 0; ky < MM; ++ky) {
        float4 t4 = *(const float4*)(tw2 + ((size_t)ky * SS + j0) * 2);
        const float* Gk = gp + ky * (DV * 2);        // 64 contiguous s_loads
        #pragma unroll
        for (int co = 0; co < DV; ++co) {
            float gr = Gk[2 * co], gi = Gk[2 * co + 1];
            acc[co].x += gr * t4.x - gi * t4.y;
            acc[co].y += gr * t4.z - gi * t4.w;
        }
    }

    if (FINAL) {
        float qb = q_b[0];
        float2 o2; o2.x = qb; o2.y = qb;
        #pragma unroll
        for (int co = 0; co < DV; ++co) {
            float qv = q_w[co];
            o2.x += qv * acc[co].x; o2.y += qv * acc[co].y;
        }
        *(float2*)(out + ((size_t)(b * SS + iy)) * SS + j0) = o2;
    } else {
        #pragma unroll
        for (int co = 0; co < DV; ++co) {
            float2 v;
            v.x = fmaxf(acc[co].x, 0.f); v.y = fmaxf(acc[co].y, 0.f);
            *(float2*)(hb + (size_t)co * SS * SS) = v;
        }
    }
}

extern "C" void kernel_launch(void* const* d_in, const int* in_sizes, int n_in,
                              void* d_out, int out_size, void* d_ws, size_t ws_size,
                              hipStream_t stream)
{
    const float* x    = (const float*)d_in[0];
    const float* p_w  = (const float*)d_in[1];
    const float* p_b  = (const float*)d_in[2];
    const float* ws_w = (const float*)d_in[3];
    const float* ws_b = (const float*)d_in[4];
    const float* w1r  = (const float*)d_in[5];
    const float* w1i  = (const float*)d_in[6];
    const float* w2r  = (const float*)d_in[7];
    const float* w2i  = (const float*)d_in[8];
    const float* q_w  = (const float*)d_in[9];
    const float* q_b  = (const float*)d_in[10];
    float* out = (float*)d_out;

    float* h   = (float*)d_ws;
    float* A   = h   + (size_t)NB * DV * SS * SS;
    float* F   = A   + (size_t)NB * MM * DV * SS * 2;
    float* g   = F   + (size_t)NB * MM * MK * DV * 2;
    float* twT = g   + (size_t)NB * SS * MM * DV * 2;
    float* wT  = twT + (size_t)SS * MM * 2;
    float* tw2 = wT  + (size_t)LL * DV * DV;

    dim3 blk(256);
    k_prep<<<1, blk, 0, stream>>>(ws_w, twT, wT, tw2);
    // lifting + row-DFT for layer 0's A, fused
    k_liftdft<<<NB * SS, blk, 0, stream>>>(x, p_w, p_b, h, twT, A);
    for (int l = 0; l < LL; ++l) {
        k_cm<<<NB * MM * 4, blk, 0, stream>>>(A, w1r, w1i, w2r, w2i, F, l);
        k_inv1<<<NB * SS, dim3(384), 0, stream>>>(F, g);
        if (l < LL - 1)
            // pointwise + row-DFT producing A for layer l+1, fused
            k_ptdft<<<NB * SS, blk, 0, stream>>>(h, g, wT, ws_b, tw2, twT, A, l);
        else
            k_pt<1><<<NB * 128, blk, 0, stream>>>(h, g, wT, ws_b, tw2,
                                                  q_w, q_b, out, l);
    }
}

// Round 2
// 677.458 us; speedup vs baseline: 1.3537x; 1.3537x over previous
//
#include <hip/hip_runtime.h>
#include <math.h>

#define NB 16    // batch
#define SS 256   // spatial size (H = W = 256)
#define DV 32    // channels
#define MM 12    // w-dim (j) modes kept
#define MK 24    // h-dim (iy) modes kept (0..11 and 244..255)
#define LL 4     // layers
#define TWO_PI_N 0.024543692606170259679f   // 2*pi/256
#define HSTR 257 // fused-kernel LDS row stride (floats): 257 % 32 = 1 -> 2-way max (free)
#define TWSOFF (DV * HSTR)                  // LDS offset of per-block seg-phase table

typedef float v2f __attribute__((ext_vector_type(2)));   // -> v_pk_fma_f32

// Workspace (floats):
//   h   : [NB][DV][SS][SS]            134 MB, in-place per layer
//   A   : [NB][SS(iy)][MM(ky)][DV][2] 12.6 MB  (row-DFT of h; iy-major = coalesced
//                                              3KB-contiguous write per fused block)
//   F   : [NB][ky:MM][m:MK][co:DV][2]  1.2 MB  (mixed spectral coeffs, pre-scaled)
//   g   : [NB][SS(iy)][MM][DV][2]     12.6 MB  (per-row spectral coeffs)
//   twT : [SS][MM][2]                  24 KB   (cos, -sin) of 2*pi*k*j/256; fused DFT
//                                              uses rows 0..31 only (block-uniform s_loads)
//   wT  : [LL][ci][co]                 16 KB   (transposed conv weights)
//   tw2 : [MM][SS][2]                  24 KB   (cos, +sin)  (inverse j-DFT, coalesced)

// --------------------------------------------- setup: tables + weight^T
__global__ __launch_bounds__(256) void k_prep(const float* __restrict__ ws_w,
        float* __restrict__ twT, float* __restrict__ wT, float* __restrict__ tw2)
{
    int j = threadIdx.x;
    #pragma unroll
    for (int k = 0; k < MM; ++k) {
        float ang = TWO_PI_N * (float)((k * j) & 255);
        float s, c; sincosf(ang, &s, &c);
        twT[j * (MM * 2) + 2 * k]     = c;
        twT[j * (MM * 2) + 2 * k + 1] = -s;
        tw2[(k * SS + j) * 2]     = c;
        tw2[(k * SS + j) * 2 + 1] = s;
    }
    for (int idx = threadIdx.x; idx < LL * DV * DV; idx += 256) {
        int l = idx >> 10, rem = idx & 1023, co = rem >> 5, ci = rem & 31;
        wT[(l * DV + ci) * DV + co] = ws_w[(l * DV + co) * DV + ci];
    }
}

// ---------------------------------------------------------------------------
// Fused row-DFT epilogue. Precondition: smem[c*HSTR + j] holds this (b,iy) row
// for all 32 channels; smem[TWSOFF + (s*MM+k)*2] holds the seg-phase table
// (cos,-sin)(2*pi*k*s/8); a __syncthreads() has been issued after both.
//
// Decomposition (keeps twiddles BLOCK-uniform -> s_loads, the R0-proven form):
//   A[k] = sum_s e^{-2pi i k s/8} * ( sum_{i<32} h[32s+i] e^{-2pi i k i/256} )
// Thread (c = tid&31, seg = tid>>5) computes the inner sum for its segment
// with 12 packed (cos,-sin) pk-FMAs per point (twiddle rows 0..31 of twT),
// applies its seg phase (12 complex mults), then 8-way LDS reduction.
// LDS h reads: addr = c*257 + seg*32 + i -> bank (c+i)%32, 2 lanes/bank = free.
// A write: 384 consecutive float2 (3KB contiguous) -> fully coalesced.
// ---------------------------------------------------------------------------
__device__ __forceinline__ void row_dft_from_lds(float* smem,
        const float* __restrict__ twT, float* __restrict__ A,
        int b, int iy, int tid)
{
    int c   = tid & 31;
    int seg = tid >> 5;          // 0..7
    int j0  = seg << 5;

    v2f arai[MM];
    #pragma unroll
    for (int k = 0; k < MM; ++k) arai[k] = (v2f)(0.f);

    const float* hp = smem + c * HSTR + j0;
    #pragma unroll 2
    for (int i = 0; i < 32; ++i) {
        float v = hp[i];
        const v2f* twj = (const v2f*)(twT + (size_t)i * (MM * 2));  // block-uniform -> s_load
        #pragma unroll
        for (int k = 0; k < MM; ++k)
            arai[k] += twj[k] * v;   // packed (cos,-sin) fma, sgpr-pair operand
    }

    // apply segment phase: arai[k] *= (pr, pi) from the LDS table
    const float* ph = smem + TWSOFF + seg * (MM * 2);
    #pragma unroll
    for (int k = 0; k < MM; ++k) {
        float pr = ph[2 * k], pi = ph[2 * k + 1];
        float re = arai[k].x * pr - arai[k].y * pi;
        float im = arai[k].x * pi + arai[k].y * pr;
        arai[k].x = re; arai[k].y = im;
    }

    __syncthreads();                       // hs/table reads done; reuse as red
    v2f* red = (v2f*)smem;                 // [tid][13] v2f (proven: 0 conflicts)
    #pragma unroll
    for (int k = 0; k < MM; ++k) red[tid * 13 + k] = arai[k];
    __syncthreads();

    // 384 outputs (k,c): consecutive o -> consecutive float2 -> coalesced 3KB
    #pragma unroll
    for (int rep = 0; rep < 2; ++rep) {
        int o = tid + rep * 256;
        if (o < 384) {
            int k = o >> 5, cc = o & 31;
            v2f s = (v2f)(0.f);
            #pragma unroll
            for (int sg = 0; sg < 8; ++sg)
                s += red[(sg * 32 + cc) * 13 + k];
            size_t off = ((((size_t)(b * SS + iy)) * MM + k) * DV + cc) * 2;
            A[off]     = s.x;
            A[off + 1] = s.y;
        }
    }
}

// build the 8x12 seg-phase table into LDS (threads 0..95); covered by the
// staging __syncthreads() in the callers.
__device__ __forceinline__ void build_segphase(float* smem, int tid)
{
    if (tid < 8 * MM) {
        int s = tid / MM, k = tid - s * MM;
        float ang = TWO_PI_N * (float)(((k * s) << 5) & 255);
        float sn, cs; sincosf(ang, &sn, &cs);
        smem[TWSOFF + 2 * tid]     = cs;
        smem[TWSOFF + 2 * tid + 1] = -sn;
    }
}

// ------------------------------------------- lifting fused with row-DFT(l=0)
// grid = NB*SS (one row per block); 256 threads, 1 px/thread.
__global__ __launch_bounds__(256, 4) void k_liftdft(const float* __restrict__ x,
        const float* __restrict__ p_w, const float* __restrict__ p_b,
        float* __restrict__ h, const float* __restrict__ twT, float* __restrict__ A)
{
    __shared__ float smem[DV * HSTR + 8 * MM * 2];   // 33.6 KB -> 4 blocks/CU
    int tid = threadIdx.x;
    int b  = blockIdx.x >> 8;
    int iy = blockIdx.x & 255;
    int j  = tid;

    build_segphase(smem, tid);

    float xv = x[((size_t)(b * SS + iy)) * SS + j];
    float gy = -1.f + 2.f * (float)iy * (1.f / 255.f);
    float gx = -1.f + 2.f * (float)j  * (1.f / 255.f);

    float* hb = h + ((size_t)b * DV * SS + iy) * SS + j;
    #pragma unroll
    for (int c = 0; c < DV; ++c) {
        float v = p_w[3*c] * xv + p_w[3*c+1] * gy + p_w[3*c+2] * gx + p_b[c];
        *(hb + (size_t)c * SS * SS) = v;
        smem[c * HSTR + j] = v;            // bank (c+j)%32: conflict-free
    }
    __syncthreads();
    row_dft_from_lds(smem, twT, A, b, iy, tid);
}

// ----------------- pointwise fused with row-DFT for the NEXT layer.
// h = relu(conv1x1(h) + invDFT(g)) in place, then A = rowDFT(h) from LDS.
// grid = NB*SS (one row per block); 256 threads, 1 px/thread.
// Phase A math identical to the R14-proven k_pt (scalar float, s_load g/w).
__global__ __launch_bounds__(256, 4) void k_ptdft(float* __restrict__ h,
        const float* __restrict__ g, const float* __restrict__ wT,
        const float* __restrict__ ws_b, const float* __restrict__ tw2,
        const float* __restrict__ twT, float* __restrict__ A, int l)
{
    __shared__ float smem[DV * HSTR + 8 * MM * 2];   // 33.6 KB -> 4 blocks/CU
    int tid = threadIdx.x;
    int b  = blockIdx.x >> 8;
    int iy = blockIdx.x & 255;
    int j  = tid;

    build_segphase(smem, tid);

    float* hb = h + ((size_t)b * DV * SS + iy) * SS + j;
    const float* wt  = wT + (size_t)l * DV * DV;     // [ci][co], uniform
    const float* wsb = ws_b + (size_t)l * DV;

    float acc[DV];
    #pragma unroll
    for (int co = 0; co < DV; ++co) acc[co] = wsb[co];

    #pragma unroll 4
    for (int ci = 0; ci < DV; ++ci) {
        float hv = *(hb + (size_t)ci * SS * SS);
        const float* wc = wt + ci * DV;              // 32 contiguous s_loads
        #pragma unroll
        for (int co = 0; co < DV; ++co) acc[co] += wc[co] * hv;
    }

    const float* gp = g + ((size_t)(b * SS + iy)) * (MM * DV * 2);  // uniform
    #pragma unroll 2
    for (int ky = 0; ky < MM; ++ky) {
        float2 t2 = *(const float2*)(tw2 + ((size_t)ky * SS + j) * 2);
        const float* Gk = gp + ky * (DV * 2);        // 64 contiguous s_loads
        #pragma unroll
        for (int co = 0; co < DV; ++co) {
            float gr = Gk[2 * co], gi = Gk[2 * co + 1];
            acc[co] += gr * t2.x - gi * t2.y;
        }
    }

    #pragma unroll
    for (int co = 0; co < DV; ++co) {
        float v = fmaxf(acc[co], 0.f);               // all fused layers relu
        *(hb + (size_t)co * SS * SS) = v;
        smem[co * HSTR + j] = v;                     // conflict-free
    }
    __syncthreads();
    row_dft_from_lds(smem, twT, A, b, iy, tid);
}

// ---------- iy-DFT of A + channel mix -> F (pre-scaled)
// A layout is now [b][iy][ky][c][2]: producer remapped to c = tid&31 so the
// 32 consecutive lanes read 32 consecutive float2 (256B coalesced) per iy.
// ch-reduction: shfl_xor(32) pairs + 4-wave LDS sum. Consumer half unchanged.
__global__ __launch_bounds__(256, 4) void k_cm(const float* __restrict__ A,
        const float* __restrict__ w1r, const float* __restrict__ w1i,
        const float* __restrict__ w2r, const float* __restrict__ w2i,
        float* __restrict__ F, int l)
{
    __shared__ float red[4][DV][7][2];       // pad 7: step-14 banks, 2-way = free
    __shared__ float FinS[DV][6][2];
    int blk = blockIdx.x;
    int mg = blk & 3;
    int bk = blk >> 2;                       // b*MM + ky
    int b  = bk / MM;
    int ky = bk - b * MM;
    int tid = threadIdx.x;
    int c = tid & 31, ch = tid >> 5;
    int iy0 = ch * 32;

    // float2 element (b, iy, ky, c):  base + iy*(MM*DV)
    const float2* Ap = (const float2*)(A) + ((size_t)(b * SS) * MM + ky) * DV + c;

    float fr[6], fi[6], pc[6], ps[6], sc[6], ssn[6];
    #pragma unroll
    for (int k = 0; k < 6; ++k) {
        int m = mg * 6 + k;
        int f = (m < MM) ? m : (232 + m);    // 244..255 for m >= 12
        float s, cc;
        sincosf(TWO_PI_N * (float)f, &s, &cc);
        sc[k] = cc; ssn[k] = s;
        sincosf(TWO_PI_N * (float)((f * iy0) & 255), &s, &cc);
        pc[k] = cc; ps[k] = s;
        fr[k] = fi[k] = 0.f;
    }
    #pragma unroll 4
    for (int i = 0; i < 32; ++i) {
        float2 a = Ap[(size_t)(iy0 + i) * (MM * DV)];
        #pragma unroll
        for (int k = 0; k < 6; ++k) {
            fr[k] += a.x * pc[k] + a.y * ps[k];   // A * e^{-i th}
            fi[k] += a.y * pc[k] - a.x * ps[k];
            float np = pc[k] * sc[k] - ps[k] * ssn[k];
            float nq = pc[k] * ssn[k] + ps[k] * sc[k];
            pc[k] = np; ps[k] = nq;
        }
    }
    // reduce ch pairs (lanes l <-> l^32 share c, adjacent ch)
    #pragma unroll
    for (int k = 0; k < 6; ++k) {
        fr[k] += __shfl_xor(fr[k], 32, 64);
        fi[k] += __shfl_xor(fi[k], 32, 64);
    }
    int wv = tid >> 6;
    if ((tid & 63) < 32) {
        #pragma unroll
        for (int k = 0; k < 6; ++k) {
            red[wv][c][k][0] = fr[k];
            red[wv][c][k][1] = fi[k];
        }
    }
    __syncthreads();
    if (tid < 192) {
        int cc = tid & 31, k2 = tid >> 5;
        float sr = 0.f, si = 0.f;
        #pragma unroll
        for (int w = 0; w < 4; ++w) {
            sr += red[w][cc][k2][0];
            si += red[w][cc][k2][1];
        }
        FinS[cc][k2][0] = sr; FinS[cc][k2][1] = si;
    }
    __syncthreads();

    // consumer: unchanged proven code (old thread mapping)
    int c2 = tid >> 3, ch2 = tid & 7;
    if (ch2 < 6) {
        int o = c2;
        int m = mg * 6 + ch2;
        const float* Wr; const float* Wi; int xm;
        if (m < MM) { Wr = w1r; Wi = w1i; xm = m; }
        else        { Wr = w2r; Wi = w2i; xm = m - MM; }
        float scale = ((ky == 0) ? 1.0f : 2.0f) * (1.0f / 65536.0f);
        float orr = 0.f, oii = 0.f;
        #pragma unroll 4
        for (int i = 0; i < DV; ++i) {
            float gr = FinS[i][ch2][0], gi = FinS[i][ch2][1];
            size_t wi = ((size_t)(l * DV + i) * DV + o) * (MM * MM) + xm * MM + ky;
            float wr = Wr[wi], wim = Wi[wi];
            orr += gr * wr - gi * wim;
            oii += gr * wim + gi * wr;
        }
        size_t off = (((size_t)bk * MK + m) * DV + o) * 2;   // [ky][m][co]
        F[off] = orr * scale; F[off + 1] = oii * scale;
    }
}

// -------------------- inverse iy-DFT: F -> g[b][iy][ky][co][2]  (unchanged)
__global__ __launch_bounds__(384) void k_inv1(const float* __restrict__ F,
        float* __restrict__ g)
{
    __shared__ float itw[MK * 2];
    int tid = threadIdx.x;
    int b = blockIdx.x >> 8, iy = blockIdx.x & 255;
    if (tid < MK) {
        int f = (tid < MM) ? tid : (232 + tid);
        float ang = TWO_PI_N * (float)((f * iy) & 255);
        float s, c; sincosf(ang, &s, &c);
        itw[2 * tid] = c; itw[2 * tid + 1] = s;
    }
    __syncthreads();

    int ky = tid >> 5, co = tid & 31;
    const float* Fp = F + ((size_t)(b * MM + ky) * MK) * (DV * 2) + 2 * co;
    float gr = 0.f, gi = 0.f;
    #pragma unroll
    for (int m = 0; m < MK; ++m) {
        float2 fv = *(const float2*)(Fp + (size_t)m * (DV * 2));  // coalesced
        float ic = itw[2 * m], is = itw[2 * m + 1];
        gr += fv.x * ic - fv.y * is;
        gi += fv.x * is + fv.y * ic;
    }
    size_t o = (((size_t)(b * SS + iy)) * MM + ky) * (DV * 2) + 2 * co;
    g[o] = gr; g[o + 1] = gi;
}

// ----------------- FINAL-layer pointwise (projection to out); no DFT needed.
// grid = NB*128; block = 2 rows x 2 j-halves, 2 px/thread. R14-proven form.
template<int FINAL>
__global__ __launch_bounds__(256, 4) void k_pt(float* __restrict__ h,
        const float* __restrict__ g, const float* __restrict__ wT,
        const float* __restrict__ ws_b, const float* __restrict__ tw2,
        const float* __restrict__ q_w, const float* __restrict__ q_b,
        float* __restrict__ out, int l)
{
    int tid = threadIdx.x;
    int lane = tid & 63;
    int w = __builtin_amdgcn_readfirstlane(tid >> 6);
    int b  = blockIdx.x >> 7;
    int iy = ((blockIdx.x & 127) << 1) + (w >> 1);
    int j0 = ((w & 1) << 7) + (lane << 1);

    float* hb = h + ((size_t)b * DV * SS + iy) * SS + j0;
    const float* wt  = wT + (size_t)l * DV * DV;     // [ci][co], uniform
    const float* wsb = ws_b + (size_t)l * DV;

    float2 acc[DV];
    #pragma unroll
    for (int co = 0; co < DV; ++co) {
        float bv = wsb[co];
        acc[co].x = bv; acc[co].y = bv;
    }

    #pragma unroll 4
    for (int ci = 0; ci < DV; ++ci) {
        float2 hv = *(const float2*)(hb + (size_t)ci * SS * SS);
        const float* wc = wt + ci * DV;              // 32 contiguous s_loads
        #pragma unroll
        for (int co = 0; co < DV; ++co) {
            float wv = wc[co];
            acc[co].x += wv * hv.x; acc[co].y += wv * hv.y;
        }
    }

    const float* gp = g + ((size_t)(b * SS + iy)) * (MM * DV * 2);  // uniform
    #pragma unroll 2
    for (int ky = 0; ky < MM; ++ky) {
        float4 t4 = *(const float4*)(tw2 + ((size_t)ky * SS + j0) * 2);
        const float* Gk = gp + ky * (DV * 2);        // 64 contiguous s_loads
        #pragma unroll
        for (int co = 0; co < DV; ++co) {
            float gr = Gk[2 * co], gi = Gk[2 * co + 1];
            acc[co].x += gr * t4.x - gi * t4.y;
            acc[co].y += gr * t4.z - gi * t4.w;
        }
    }

    if (FINAL) {
        float qb = q_b[0];
        float2 o2; o2.x = qb; o2.y = qb;
        #pragma unroll
        for (int co = 0; co < DV; ++co) {
            float qv = q_w[co];
            o2.x += qv * acc[co].x; o2.y += qv * acc[co].y;
        }
        *(float2*)(out + ((size_t)(b * SS + iy)) * SS + j0) = o2;
    } else {
        #pragma unroll
        for (int co = 0; co < DV; ++co) {
            float2 v;
            v.x = fmaxf(acc[co].x, 0.f); v.y = fmaxf(acc[co].y, 0.f);
            *(float2*)(hb + (size_t)co * SS * SS) = v;
        }
    }
}

extern "C" void kernel_launch(void* const* d_in, const int* in_sizes, int n_in,
                              void* d_out, int out_size, void* d_ws, size_t ws_size,
                              hipStream_t stream)
{
    const float* x    = (const float*)d_in[0];
    const float* p_w  = (const float*)d_in[1];
    const float* p_b  = (const float*)d_in[2];
    const float* ws_w = (const float*)d_in[3];
    const float* ws_b = (const float*)d_in[4];
    const float* w1r  = (const float*)d_in[5];
    const float* w1i  = (const float*)d_in[6];
    const float* w2r  = (const float*)d_in[7];
    const float* w2i  = (const float*)d_in[8];
    const float* q_w  = (const float*)d_in[9];
    const float* q_b  = (const float*)d_in[10];
    float* out = (float*)d_out;

    float* h   = (float*)d_ws;
    float* A   = h   + (size_t)NB * DV * SS * SS;
    float* F   = A   + (size_t)NB * SS * MM * DV * 2;
    float* g   = F   + (size_t)NB * MM * MK * DV * 2;
    float* twT = g   + (size_t)NB * SS * MM * DV * 2;
    float* wT  = twT + (size_t)SS * MM * 2;
    float* tw2 = wT  + (size_t)LL * DV * DV;

    dim3 blk(256);
    k_prep<<<1, blk, 0, stream>>>(ws_w, twT, wT, tw2);
    // lifting + row-DFT for layer 0's A, fused
    k_liftdft<<<NB * SS, blk, 0, stream>>>(x, p_w, p_b, h, twT, A);
    for (int l = 0; l < LL; ++l) {
        k_cm<<<NB * MM * 4, blk, 0, stream>>>(A, w1r, w1i, w2r, w2i, F, l);
        k_inv1<<<NB * SS, dim3(384), 0, stream>>>(F, g);
        if (l < LL - 1)
            // pointwise + row-DFT producing A for layer l+1, fused
            k_ptdft<<<NB * SS, blk, 0, stream>>>(h, g, wT, ws_b, tw2, twT, A, l);
        else
            k_pt<1><<<NB * 128, blk, 0, stream>>>(h, g, wT, ws_b, tw2,
                                                  q_w, q_b, out, l);
    }
}